// Round 1
// 3690.144 us; speedup vs baseline: 7.2673x; 7.2673x over previous
//
#include <hip/hip_runtime.h>

// CRF loss, T=16384, L=1024. v9: algorithmic de-serialization.
// v8 was latency-bound: 8192 sequential 64-wave MALL-seqlock steps x ~3.3us
// (VALUBusy 3.2%, HBM 0.26%). v9 exploits Perron-Frobenius contraction:
// exp-space recurrence a_t = D_t E a_{t-1} (E=exp(trans)>0) means chunk
// products P_c over B=1024 steps are numerically exactly rank-1
// ((lam2/lam1)^1024 ~ 0). Skeleton P_c ~= y_c z_c^T/(1^T y_c),
// y_c = P_c*1 (fwd chunk from ones), z_c = P_c^T*1 (bwd chunk from ones).
// Stitch (f64): score = NEG + sum_{c<15}[log(z_{c+1}.y_c)] - sum_c log(1.y_c)
//               + log z_0[START] + sum_c tau_c   (y-scales cancel exactly;
// s = exp(trans[STOP,:]) = e^NEG * ones -> constant NEG).
// Topology: 16 chunks/dir x 8 parties = 256 blocks, 1 block/CU (VGPR~340
// forces it) -> all co-resident. Party = 256 threads holding 128 rows x all
// cols of E as f16 in 256 VGPRs. Per step: 256 dot2/lane, 3-hop butterfly,
// publish 64 self-tagged u64 (f16 pair | tag, v8 protocol, parity-dbuf),
// all-gather 512 words from 8 parties via MALL, stage swizzled f16 in LDS.
// Sequential depth 8192 -> 1024, 32 groups concurrent.

#define TT    16384
#define LLAB  1024
#define NEGV  -10000.0
#define NCH   16            // chunks per direction
#define BST   (TT / NCH)    // 1024 sequential steps per chunk
#define NPTY  8             // parties (CUs) per chunk group
#define AGT   __HIP_MEMORY_SCOPE_AGENT

typedef unsigned long long u64;
typedef unsigned int u32;
typedef unsigned short u16;
typedef _Float16 h2 __attribute__((ext_vector_type(2)));

__device__ __forceinline__ void pub(u64* p, u64 v) {
  __hip_atomic_store(p, v, __ATOMIC_RELAXED, AGT);
}
__device__ __forceinline__ u64 aload(const u64* p) {
  return __hip_atomic_load(p, __ATOMIC_RELAXED, AGT);
}
__device__ __forceinline__ u32 pack2(float a, float b) {
  h2 h = {(_Float16)a, (_Float16)b};
  return __builtin_bit_cast(u32, h);
}
__device__ __forceinline__ float f16lo(u32 b) {
  return (float)__builtin_bit_cast(_Float16, (u16)(b & 0xFFFFu));
}
__device__ __forceinline__ float f16hi(u32 b) {
  return (float)__builtin_bit_cast(_Float16, (u16)(b >> 16));
}
#if __has_builtin(__builtin_amdgcn_fdot2)
__device__ __forceinline__ float dot2(u32 w, u32 a, float c) {
  return __builtin_amdgcn_fdot2(__builtin_bit_cast(h2, w),
                                __builtin_bit_cast(h2, a), c, false);
}
#else
__device__ __forceinline__ float dot2(u32 w, u32 a, float c) {
  h2 hw = __builtin_bit_cast(h2, w), ha = __builtin_bit_cast(h2, a);
  return c + (float)hw[0] * (float)ha[0] + (float)hw[1] * (float)ha[1];
}
#endif

// swizzled LDS slot for h2-pair word w (0..511): rotate 4-word blocks within
// each 64-word (per-cg) region by 2*region -> conflict-free ds_read_b128.
__device__ __forceinline__ int qpos(int w) {
  int r = w >> 6;
  return 64 * r + 4 * ((((w >> 2) & 15) + 2 * r) & 15) + (w & 3);
}

// ---------------- gold path score (unchanged, proven) ----------------
__global__ __launch_bounds__(256) void crf_gold(const float* __restrict__ pred,
                                                const int* __restrict__ ref,
                                                const float* __restrict__ trans,
                                                float* __restrict__ gold) {
  int t = blockIdx.x * 256 + threadIdx.x;
  int r = ref[t];
  int prev = (t == 0) ? (LLAB - 2) : ref[t - 1];    // START = L-2
  float v = trans[(size_t)r * LLAB + prev] + pred[(size_t)t * LLAB + r];
  if (t == TT - 1) v += trans[(size_t)(LLAB - 1) * LLAB + r];  // STOP row
#pragma unroll
  for (int off = 32; off >= 1; off >>= 1) v += __shfl_xor(v, off);
  __shared__ float acc[4];
  if ((threadIdx.x & 63) == 0) acc[threadIdx.x >> 6] = v;
  __syncthreads();
  if (threadIdx.x == 0) atomicAdd(gold, acc[0] + acc[1] + acc[2] + acc[3]);
}

// ---------------- chunked fwd/bwd propagation ----------------
__global__ __launch_bounds__(256, 1) void crf_chunks(
    const float* __restrict__ pred, const float* __restrict__ trans,
    u64* __restrict__ pbuf, float* __restrict__ ybuf,
    float* __restrict__ zbuf, double* __restrict__ tlog) {
  const int tid = threadIdx.x;           // 0..255
  const int wv  = tid >> 6;              // wave 0..3
  const int l   = tid & 63;
  const int rg  = l >> 3, cg = l & 7;
  const int b   = blockIdx.x;            // 0..255
  const int k   = b >> 3;                // chunk-task 0..31
  const int party = b & 7;
  const bool isFwd = (k < NCH);
  const int c = isFwd ? k : (k - NCH);
  const int tbase = c * BST;
  const int rowbase = 128 * party + 32 * wv + 4 * rg;  // this lane's 4 rows
  const int colbase = 128 * cg;                        // this lane's 128 cols

  // ---- W fragment: 4 rows x 64 f16 col-pairs = 256 VGPRs.
  // fwd: W[j][i] = exp(trans[row][col]); bwd (E^T): exp(trans[col][row]).
  u32 wpk[4][64];
#pragma unroll
  for (int j = 0; j < 4; ++j) {
    const int row = rowbase + j;
    if (isFwd) {
      const float2* t2 = (const float2*)&trans[(size_t)row * LLAB + colbase];
#pragma unroll
      for (int m = 0; m < 64; ++m) {
        float2 v = t2[m];
        wpk[j][m] = pack2(__expf(v.x), __expf(v.y));
      }
    } else {
#pragma unroll
      for (int m = 0; m < 64; ++m) {
        float a = trans[(size_t)(colbase + 2 * m) * LLAB + row];
        float bb = trans[(size_t)(colbase + 2 * m + 1) * LLAB + row];
        wpk[j][m] = pack2(__expf(a), __expf(bb));
      }
    }
  }

  __shared__ __attribute__((aligned(16))) u32 qbuf[2][512];
  __shared__ float smax[2][4];

  u64* grp = pbuf + (size_t)k * (NPTY * 2 * 64);
  u64* mypub = grp + (size_t)(party * 2) * 64;

  // ---- init state (parity 0): fwd = ones; bwd = exp(feat_last). Local only.
  {
    float mm = 0.0f;
#pragma unroll
    for (int h = 0; h < 2; ++h) {
      int w = tid + 256 * h;
      float a0 = 1.0f, a1 = 1.0f;
      if (!isFwd) {
        const float2* pp =
            (const float2*)&pred[(size_t)(tbase + BST - 1) * LLAB + 2 * w];
        float2 e = pp[0];
        a0 = __expf(e.x); a1 = __expf(e.y);
      }
      qbuf[0][qpos(w)] = pack2(a0, a1);
      mm = fmaxf(mm, fmaxf(a0, a1));
    }
#pragma unroll
    for (int off = 32; off >= 1; off >>= 1) mm = fmaxf(mm, __shfl_xor(mm, off));
    if (l == 0) smax[0][wv] = mm;
  }
  __syncthreads();

  const float C0 = 13359.727f;  // e^9.5 growth prior; u self-corrects residue
  double up = 1.0, tacc = 0.0;

  for (int s = 0; s < BST; ++s) {
    const int p = s & 1;
    // global max of staged q (consistent across parties: same f16 words)
    float u = fmaxf(fmaxf(smax[p][0], smax[p][1]), fmaxf(smax[p][2], smax[p][3]));
    up *= (double)u;
    if ((s & 63) == 63) { tacc += log(up); up = 1.0; }
    const float inv = 1.0f / (C0 * u);

    const bool doEmit = isFwd || (s < BST - 1);
    const int trow = isFwd ? (tbase + s) : (doEmit ? (tbase + BST - 2 - s) : 0);
    float4 fr4 = {0.f, 0.f, 0.f, 0.f};
    if (cg == 0) fr4 = *(const float4*)&pred[(size_t)trow * LLAB + rowbase];

    // dots: 4 rows x 128 cols, q from swizzled LDS
    float p4[4] = {0.f, 0.f, 0.f, 0.f};
#pragma unroll
    for (int be = 0; be < 16; ++be) {
      const uint4 v = *(const uint4*)&qbuf[p][64 * cg + 4 * ((be + 2 * cg) & 15)];
#pragma unroll
      for (int j = 0; j < 4; ++j) {
        p4[j] = dot2(wpk[j][4 * be + 0], v.x, p4[j]);
        p4[j] = dot2(wpk[j][4 * be + 1], v.y, p4[j]);
        p4[j] = dot2(wpk[j][4 * be + 2], v.z, p4[j]);
        p4[j] = dot2(wpk[j][4 * be + 3], v.w, p4[j]);
      }
    }
    // reduce over the 8 col-group lanes (cg = low 3 bits)
#pragma unroll
    for (int off = 1; off <= 4; off <<= 1) {
#pragma unroll
      for (int j = 0; j < 4; ++j) p4[j] += __shfl_xor(p4[j], off);
    }

    const u64 tg = (u64)(u32)(s + 1);
    if (s == BST - 1) {
      // final step: write normalized chunk vector (f32) straight to global
      if (cg == 0) {
        float e0 = 1.f, e1 = 1.f, e2 = 1.f, e3 = 1.f;
        if (doEmit) {
          e0 = __expf(fr4.x); e1 = __expf(fr4.y);
          e2 = __expf(fr4.z); e3 = __expf(fr4.w);
        }
        float4 o = {p4[0] * e0 * inv, p4[1] * e1 * inv,
                    p4[2] * e2 * inv, p4[3] * e3 * inv};
        float* dst = isFwd ? ybuf : zbuf;
        *(float4*)&dst[(size_t)c * LLAB + rowbase] = o;
      }
    } else {
      // publish own 128 rows as 64 tagged words (writers: cg==0, 2 words each)
      if (cg == 0) {
        float e0 = __expf(fr4.x), e1 = __expf(fr4.y);
        float e2 = __expf(fr4.z), e3 = __expf(fr4.w);
        float o0 = p4[0] * e0 * inv, o1 = p4[1] * e1 * inv;
        float o2 = p4[2] * e2 * inv, o3 = p4[3] * e3 * inv;
        int widx = 16 * wv + 2 * rg;
        pub(mypub + (size_t)p * 64 + widx,     (((u64)pack2(o0, o1)) << 32) | tg);
        pub(mypub + (size_t)p * 64 + widx + 1, (((u64)pack2(o2, o3)) << 32) | tg);
      }
      // all-gather 512 words from 8 parties (incl own), combined 2-word spin
      int w0 = tid, w1 = tid + 256;
      const u64* rp0 = grp + ((size_t)(w0 >> 6) * 2 + p) * 64 + (w0 & 63);
      const u64* rp1 = grp + ((size_t)(w1 >> 6) * 2 + p) * 64 + (w1 & 63);
      u64 pw0 = 0, pw1 = 0;
      bool d0 = false, d1 = false;
      do {
        if (!d0) { pw0 = aload(rp0); d0 = ((u32)pw0 == (u32)tg); }
        if (!d1) { pw1 = aload(rp1); d1 = ((u32)pw1 == (u32)tg); }
      } while (!__all(d0 && d1));
      u32 pay0 = (u32)(pw0 >> 32), pay1 = (u32)(pw1 >> 32);
      qbuf[p ^ 1][qpos(w0)] = pay0;
      qbuf[p ^ 1][qpos(w1)] = pay1;
      float mm = fmaxf(fmaxf(f16lo(pay0), f16hi(pay0)),
                       fmaxf(f16lo(pay1), f16hi(pay1)));
#pragma unroll
      for (int off = 32; off >= 1; off >>= 1) mm = fmaxf(mm, __shfl_xor(mm, off));
      if (l == 0) smax[p ^ 1][wv] = mm;
      __syncthreads();
    }
  }
  // tau_c = sum_s log(C0 * u_s); store sum log(u) part (BST*log C0 in stitch)
  if (party == 0 && tid == 0) tlog[k] = tacc;
}

// ---------------- rank-1 stitch in f64 ----------------
__global__ __launch_bounds__(256) void crf_stitch(
    const float* __restrict__ ybuf, const float* __restrict__ zbuf,
    const double* __restrict__ tlog, const float* __restrict__ trans,
    const float* __restrict__ gold, float* __restrict__ out) {
  const int tid = threadIdx.x;
  __shared__ double red[2][4];
  double score = 0.0;
  for (int cc = 0; cc < NCH; ++cc) {
    double na = 0.0, sa = 0.0;
    for (int j = tid; j < LLAB; j += 256) {
      double yv = (double)ybuf[(size_t)cc * LLAB + j];
      na += yv;
      // seam above chunk cc; last seam is s = exp(trans[STOP,:]) = e^NEG * 1
      double zz = (cc + 1 < NCH) ? (double)zbuf[(size_t)(cc + 1) * LLAB + j]
                                 : 1.0;
      sa += zz * yv;
    }
#pragma unroll
    for (int off = 32; off >= 1; off >>= 1) {
      na += __shfl_xor(na, off);
      sa += __shfl_xor(sa, off);
    }
    if ((tid & 63) == 0) { red[0][tid >> 6] = na; red[1][tid >> 6] = sa; }
    __syncthreads();
    if (tid == 0) {
      double n = red[0][0] + red[0][1] + red[0][2] + red[0][3];
      double sm = red[1][0] + red[1][1] + red[1][2] + red[1][3];
      score += log(sm) - log(n);
    }
    __syncthreads();
  }
  if (tid == 0) {
    const double LC0 = log((double)13359.727f);
    double t = 0.0;
    for (int cc = 0; cc < NCH; ++cc) t += tlog[NCH + cc] + (double)BST * LC0;
    score += t;
    score += log((double)zbuf[LLAB - 2]);  // z_0[START=1022]
    score += NEGV;                         // the exp(trans[STOP,:]) factor
    out[0] = (float)(score - (double)gold[0]);
  }
}

extern "C" void kernel_launch(void* const* d_in, const int* in_sizes, int n_in,
                              void* d_out, int out_size, void* d_ws, size_t ws_size,
                              hipStream_t stream) {
  const float* pred  = (const float*)d_in[0];   // (16384, 1024) f32
  const int*   ref   = (const int*)d_in[1];     // (16384,) i32
  const float* trans = (const float*)d_in[2];   // (1024, 1024) f32
  float* out = (float*)d_out;

  char* ws = (char*)d_ws;
  float* gold = (float*)(ws + 0);                          // 4 B (pad 1024)
  u64* pbuf   = (u64*)(ws + 1024);                         // 32*8*2*64*8 = 256 KB
  size_t off = 1024 + (size_t)32 * NPTY * 2 * 64 * 8;
  float* ybuf = (float*)(ws + off); off += (size_t)NCH * LLAB * 4;  // 64 KB
  float* zbuf = (float*)(ws + off); off += (size_t)NCH * LLAB * 4;  // 64 KB
  double* tlog = (double*)(ws + off);                      // 32 * 8 B

  hipMemsetAsync(ws, 0, 256, stream);                      // gold accumulator
  hipMemsetAsync(pbuf, 0, (size_t)32 * NPTY * 2 * 64 * 8, stream);  // tags
  crf_gold<<<64, 256, 0, stream>>>(pred, ref, trans, gold);
  crf_chunks<<<256, 256, 0, stream>>>(pred, trans, pbuf, ybuf, zbuf, tlog);
  crf_stitch<<<1, 256, 0, stream>>>(ybuf, zbuf, tlog, trans, gold, out);
}

// Round 2
// 1032.136 us; speedup vs baseline: 25.9823x; 3.5753x over previous
//
#include <hip/hip_runtime.h>

// CRF loss, T=16384, L=1024. v10: chunk-batched MFMA + 64-deep pipeline.
// v9 was exchange-latency bound: 1024 sequential steps x ~3.6us (2.8us MALL
// seqlock RT + 0.8us dot2). v10: Perron contraction supports B=64-step chunks
// (rank-1 to 1e-88), so batch k=16 chunks per 8-party group (one MFMA N-tile).
// 256 chunks/dir, 32 groups x 8 parties = 256 blocks (all co-resident).
// Party holds 128 rows x 1024 cols of E (f16 MFMA A-frags, 256 regs). Per step:
// gather 1024x16 state (8KB/party publish, tagged-u64 seqlock, parity dbuf),
// stage chunk-major XOR-swizzled LDS, 32 ds_read_b128 + 64 mfma/wave, fold
// emissions (fwd output-side; bwd input-side folded at publish), normalize by
// per-chunk staged max (C0=e^9.5 prior, f64 log tracking). Depth 1024 -> 64.
// Stitch: score = NEG + sum log(z_{c+1}.y_c) - sum log(1.y_c) + log z_0[START]
//         + sum tau_bwd  (fwd tau cancels; 256 seams, f64, atomicAdd).

#define TT    16384
#define LLAB  1024
#define NEGV  -10000.0
#define BQ    64            // steps per chunk
#define NCH   256           // chunks per direction (TT/BQ)
#define KCH   16            // chunks per group (= MFMA N)
#define NPTY  8             // parties per group
#define AGT   __HIP_MEMORY_SCOPE_AGENT

typedef unsigned long long u64;
typedef unsigned int u32;
typedef unsigned short u16;
typedef _Float16 f16;
typedef _Float16 h2 __attribute__((ext_vector_type(2)));
typedef _Float16 f16x8 __attribute__((ext_vector_type(8)));
typedef float f32x4 __attribute__((ext_vector_type(4)));

__device__ __forceinline__ void pub(u64* p, u64 v) {
  __hip_atomic_store(p, v, __ATOMIC_RELAXED, AGT);
}
__device__ __forceinline__ u64 aload(const u64* p) {
  return __hip_atomic_load(p, __ATOMIC_RELAXED, AGT);
}
__device__ __forceinline__ u32 pack2(float a, float b) {
  h2 h = {(f16)a, (f16)b};
  return __builtin_bit_cast(u32, h);
}
__device__ __forceinline__ float f16lo(u32 b) {
  return (float)__builtin_bit_cast(f16, (u16)(b & 0xFFFFu));
}
__device__ __forceinline__ float f16hi(u32 b) {
  return (float)__builtin_bit_cast(f16, (u16)(b >> 16));
}
// swizzled LDS u32-index for (chunk n, byte-offset bo within its 2KB block).
// XOR of byte bits 4..6 with n&7: B-frag/max reads & stage writes all 2-way max.
__device__ __forceinline__ int qidx(int n, int bo) {
  return (((n << 11) + bo) ^ ((n & 7) << 4)) >> 2;
}

// ---------------- gold path score (unchanged, proven) ----------------
__global__ __launch_bounds__(256) void crf_gold(const float* __restrict__ pred,
                                                const int* __restrict__ ref,
                                                const float* __restrict__ trans,
                                                float* __restrict__ gold) {
  int t = blockIdx.x * 256 + threadIdx.x;
  int r = ref[t];
  int prev = (t == 0) ? (LLAB - 2) : ref[t - 1];    // START = L-2
  float v = trans[(size_t)r * LLAB + prev] + pred[(size_t)t * LLAB + r];
  if (t == TT - 1) v += trans[(size_t)(LLAB - 1) * LLAB + r];  // STOP row
#pragma unroll
  for (int off = 32; off >= 1; off >>= 1) v += __shfl_xor(v, off);
  __shared__ float acc[4];
  if ((threadIdx.x & 63) == 0) acc[threadIdx.x >> 6] = v;
  __syncthreads();
  if (threadIdx.x == 0) atomicAdd(gold, acc[0] + acc[1] + acc[2] + acc[3]);
}

// ---------------- transpose trans (for bwd row-major frag loads) -------------
__global__ __launch_bounds__(256) void transpose_k(const float* __restrict__ in,
                                                   float* __restrict__ out) {
  __shared__ float t[32][33];
  int bx = blockIdx.x & 31, by = blockIdx.x >> 5;
  int r0 = by * 32, c0 = bx * 32;
  int lr = threadIdx.x >> 3;        // 0..31
  int lc = threadIdx.x & 7;         // 8 x float4
  float4 v = *(const float4*)&in[(size_t)(r0 + lr) * LLAB + c0 + 4 * lc];
  t[lr][4 * lc] = v.x; t[lr][4 * lc + 1] = v.y;
  t[lr][4 * lc + 2] = v.z; t[lr][4 * lc + 3] = v.w;
  __syncthreads();
  float4 o = {t[4 * lc][lr], t[4 * lc + 1][lr], t[4 * lc + 2][lr], t[4 * lc + 3][lr]};
  *(float4*)&out[(size_t)(c0 + lr) * LLAB + r0 + 4 * lc] = o;
}

// ---------------- chunk-batched fwd/bwd propagation ----------------
__global__ __launch_bounds__(256, 1) void crf_chunks(
    const float* __restrict__ pred, const float* __restrict__ trans,
    const float* __restrict__ transT, u64* __restrict__ pbuf,
    float* __restrict__ ybuf, float* __restrict__ zbuf,
    double* __restrict__ tlog) {
  const int tid = threadIdx.x;
  const int wv = tid >> 6, l = tid & 63;
  const int lm = l & 15, lg = l >> 4;        // chunk-lane / k-group
  const int b = blockIdx.x;
  const int g = b & 31;                      // group (same XCD for all parties)
  const int party = b >> 5;                  // 0..7
  const bool isFwd = (g < 16);
  const int cbase = (g & 15) * KCH;
  const int myChunk = cbase + lm;
  const int tb = myChunk * BQ;
  const int wb = 128 * party + 32 * wv;      // wave's first output row

  // ---- E fragments: A[m=lm][k=32*kt+8*lg+j] = exp(M[row][k]); M=trans (fwd)
  // or transT (bwd: A' = E^T rows = trans columns = transT rows).
  const float* M = isFwd ? trans : transT;
  f16x8 afrag0[32], afrag1[32];
  {
    const float4* rp0 = (const float4*)&M[(size_t)(wb + lm) * LLAB];
    const float4* rp1 = (const float4*)&M[(size_t)(wb + 16 + lm) * LLAB];
#pragma unroll
    for (int kt = 0; kt < 32; ++kt) {
      float4 a = rp0[8 * kt + 2 * lg], c = rp0[8 * kt + 2 * lg + 1];
      f16x8 f;
      f[0] = (f16)__expf(a.x); f[1] = (f16)__expf(a.y);
      f[2] = (f16)__expf(a.z); f[3] = (f16)__expf(a.w);
      f[4] = (f16)__expf(c.x); f[5] = (f16)__expf(c.y);
      f[6] = (f16)__expf(c.z); f[7] = (f16)__expf(c.w);
      afrag0[kt] = f;
      a = rp1[8 * kt + 2 * lg]; c = rp1[8 * kt + 2 * lg + 1];
      f[0] = (f16)__expf(a.x); f[1] = (f16)__expf(a.y);
      f[2] = (f16)__expf(a.z); f[3] = (f16)__expf(a.w);
      f[4] = (f16)__expf(c.x); f[5] = (f16)__expf(c.y);
      f[6] = (f16)__expf(c.z); f[7] = (f16)__expf(c.w);
      afrag1[kt] = f;
    }
  }

  __shared__ __attribute__((aligned(16))) u32 qs[8192];   // [16 chunks][1024 f16]
  __shared__ float smax[16];

  // ---- init state: fwd = ones; bwd = exp(feat[tb+63]) per chunk
  if (isFwd) {
#pragma unroll 4
    for (int j = 0; j < 32; ++j) {
      int idx = tid + 256 * j;
      qs[qidx(idx >> 9, (idx & 511) << 2)] = 0x3C003C00u;
    }
    if (tid < 16) smax[tid] = 1.0f;
    __syncthreads();
  } else {
#pragma unroll 4
    for (int j = 0; j < 32; ++j) {
      int idx = tid + 256 * j;
      int n = idx >> 9, kw = idx & 511;
      int trow = (cbase + n) * BQ + BQ - 1;
      float2 e = *(const float2*)&pred[(size_t)trow * LLAB + 2 * kw];
      qs[qidx(n, kw << 2)] = pack2(__expf(e.x), __expf(e.y));
    }
    __syncthreads();
    {  // per-chunk max
      int n = tid >> 4, s16 = tid & 15;
      float mm = 0.f;
#pragma unroll
      for (int q = 0; q < 8; ++q) {
        uint4 v = *(const uint4*)&qs[qidx(n, 16 * s16 + 256 * q)];
        mm = fmaxf(mm, fmaxf(f16lo(v.x), f16hi(v.x)));
        mm = fmaxf(mm, fmaxf(f16lo(v.y), f16hi(v.y)));
        mm = fmaxf(mm, fmaxf(f16lo(v.z), f16hi(v.z)));
        mm = fmaxf(mm, fmaxf(f16lo(v.w), f16hi(v.w)));
      }
#pragma unroll
      for (int off = 1; off <= 8; off <<= 1) mm = fmaxf(mm, __shfl_xor(mm, off));
      if (s16 == 0) smax[n] = mm;
    }
    __syncthreads();
  }

  // emission prefetch for step 0 (fwd: t=tb; bwd: t=tb+62, input-side at publish)
  float4 fe0, fe1;
  {
    int tn = isFwd ? tb : (tb + BQ - 2);
    fe0 = *(const float4*)&pred[(size_t)tn * LLAB + wb + 4 * lg];
    fe1 = *(const float4*)&pred[(size_t)tn * LLAB + wb + 16 + 4 * lg];
  }

  const float C0 = 13359.727f;   // e^9.5 growth prior; residual tracked via u
  double up = 1.0;
  u64* grp = pbuf + (size_t)g * (2 * NPTY * 1024);

  for (int s = 0; s < BQ; ++s) {
    const bool lastS = (s == BQ - 1);
    const float u = smax[lm];
    if (tid < 16) up *= (double)smax[tid];
    const float inv = 1.0f / (C0 * u);

    // MFMA: 2 row-tiles x 32 k-tiles; B-frag from swizzled LDS
    f32x4 acc0 = {0.f, 0.f, 0.f, 0.f}, acc1 = {0.f, 0.f, 0.f, 0.f};
#pragma unroll
    for (int kt = 0; kt < 32; ++kt) {
      f16x8 bf = __builtin_bit_cast(f16x8,
          *(const uint4*)&qs[qidx(lm, 64 * kt + 16 * lg)]);
      acc0 = __builtin_amdgcn_mfma_f32_16x16x32_f16(afrag0[kt], bf, acc0, 0, 0, 0);
      acc1 = __builtin_amdgcn_mfma_f32_16x16x32_f16(afrag1[kt], bf, acc1, 0, 0, 0);
    }

    // prefetch next step's emission rows (in flight across publish+spin)
    float4 nf0 = fe0, nf1 = fe1;
    if (!lastS) {
      int sn = s + 1;
      int tn = isFwd ? (tb + sn) : (tb + BQ - 2 - sn);
      if (tn < tb) tn = tb;      // bwd sn=63 value unused
      nf0 = *(const float4*)&pred[(size_t)tn * LLAB + wb + 4 * lg];
      nf1 = *(const float4*)&pred[(size_t)tn * LLAB + wb + 16 + 4 * lg];
    }

    // fold emission (fwd: always, output-side; bwd: all but last, input-side
    // for the NEXT matvec, folded into this publish) + normalize
    const bool fold = isFwd || !lastS;
    float o0[4], o1[4];
    if (fold) {
      o0[0] = acc0[0] * __expf(fe0.x) * inv; o0[1] = acc0[1] * __expf(fe0.y) * inv;
      o0[2] = acc0[2] * __expf(fe0.z) * inv; o0[3] = acc0[3] * __expf(fe0.w) * inv;
      o1[0] = acc1[0] * __expf(fe1.x) * inv; o1[1] = acc1[1] * __expf(fe1.y) * inv;
      o1[2] = acc1[2] * __expf(fe1.z) * inv; o1[3] = acc1[3] * __expf(fe1.w) * inv;
    } else {
#pragma unroll
      for (int r = 0; r < 4; ++r) { o0[r] = acc0[r] * inv; o1[r] = acc1[r] * inv; }
    }

    if (lastS) {  // write final chunk vector (f32) to global
      float* dst = isFwd ? ybuf : zbuf;
      size_t base = (size_t)myChunk * LLAB + wb + 4 * lg;
#pragma unroll
      for (int r = 0; r < 4; ++r) {
        dst[base + r] = o0[r];
        dst[base + 16 + r] = o1[r];
      }
      break;
    }

    // publish 4 tagged words: word v = lm*64 + klocal/2
    {
      const u64 tg = (u64)(u32)(s + 1);
      u64* op = grp + ((size_t)(s & 1) * NPTY + party) * 1024;
      int v0 = lm * 64 + 16 * wv + 2 * lg;        // rt=0 rows
      pub(op + v0,     (((u64)pack2(o0[0], o0[1])) << 32) | tg);
      pub(op + v0 + 1, (((u64)pack2(o0[2], o0[3])) << 32) | tg);
      int v1 = v0 + 8;                            // rt=1 rows
      pub(op + v1,     (((u64)pack2(o1[0], o1[1])) << 32) | tg);
      pub(op + v1 + 1, (((u64)pack2(o1[2], o1[3])) << 32) | tg);
    }

    __syncthreads();   // all qs reads (MFMA/max) done before gather overwrites

    // gather all 8 parties' slices (32 words/thread), stage into swizzled LDS
    {
      const u64* gp = grp + (size_t)(s & 1) * (NPTY * 1024);
      const u32 want = (u32)(s + 1);
      u32 pend = 0xFFFFFFFFu;
      while (pend) {
        for (int j = 0; j < 32; ++j) {
          u32 bit = 1u << j;
          if (pend & bit) {
            u64 w = aload(gp + tid + 256 * j);
            if ((u32)w == want) {
              int idx = tid + 256 * j;
              int p2 = idx >> 10, v2 = idx & 1023;
              qs[qidx(v2 >> 6, 256 * p2 + 4 * (v2 & 63))] = (u32)(w >> 32);
              pend &= ~bit;
            }
          }
        }
      }
    }
    __syncthreads();   // staging complete

    {  // per-chunk max of new state
      int n = tid >> 4, s16 = tid & 15;
      float mm = 0.f;
#pragma unroll
      for (int q = 0; q < 8; ++q) {
        uint4 v = *(const uint4*)&qs[qidx(n, 16 * s16 + 256 * q)];
        mm = fmaxf(mm, fmaxf(f16lo(v.x), f16hi(v.x)));
        mm = fmaxf(mm, fmaxf(f16lo(v.y), f16hi(v.y)));
        mm = fmaxf(mm, fmaxf(f16lo(v.z), f16hi(v.z)));
        mm = fmaxf(mm, fmaxf(f16lo(v.w), f16hi(v.w)));
      }
#pragma unroll
      for (int off = 1; off <= 8; off <<= 1) mm = fmaxf(mm, __shfl_xor(mm, off));
      if (s16 == 0) smax[n] = mm;
    }
    __syncthreads();   // smax ready
    fe0 = nf0; fe1 = nf1;
  }

  // record bwd tau (log u products; stitch adds BQ*log(C0)); fwd tau cancels
  if (!isFwd && party == 0 && tid < 16) tlog[cbase + tid] = log(up);
}

// ---------------- rank-1 stitch: one block per seam, f64 ----------------
__global__ __launch_bounds__(256) void crf_stitch(
    const float* __restrict__ ybuf, const float* __restrict__ zbuf,
    const double* __restrict__ tlog, double* __restrict__ dacc) {
  const int cc = blockIdx.x, tid = threadIdx.x;
  double na = 0.0, sa = 0.0;
  for (int j = tid; j < LLAB; j += 256) {
    double yv = (double)ybuf[(size_t)cc * LLAB + j];
    na += yv;
    double zz = (cc + 1 < NCH) ? (double)zbuf[(size_t)(cc + 1) * LLAB + j] : 1.0;
    sa += zz * yv;
  }
#pragma unroll
  for (int off = 32; off >= 1; off >>= 1) {
    na += __shfl_xor(na, off);
    sa += __shfl_xor(sa, off);
  }
  __shared__ double red[2][4];
  if ((tid & 63) == 0) { red[0][tid >> 6] = na; red[1][tid >> 6] = sa; }
  __syncthreads();
  if (tid == 0) {
    double n = red[0][0] + red[0][1] + red[0][2] + red[0][3];
    double sm = red[1][0] + red[1][1] + red[1][2] + red[1][3];
    const double LC0 = log((double)13359.727f);
    atomicAdd(dacc, log(sm) - log(n) + tlog[cc] + (double)BQ * LC0);
  }
}

__global__ void crf_final(const double* __restrict__ dacc,
                          const float* __restrict__ zbuf,
                          const float* __restrict__ gold,
                          float* __restrict__ out) {
  double s = dacc[0] + log((double)zbuf[LLAB - 2]) + NEGV - (double)gold[0];
  out[0] = (float)s;
}

extern "C" void kernel_launch(void* const* d_in, const int* in_sizes, int n_in,
                              void* d_out, int out_size, void* d_ws, size_t ws_size,
                              hipStream_t stream) {
  const float* pred  = (const float*)d_in[0];   // (16384, 1024) f32
  const int*   ref   = (const int*)d_in[1];     // (16384,) i32
  const float* trans = (const float*)d_in[2];   // (1024, 1024) f32
  float* out = (float*)d_out;

  char* ws = (char*)d_ws;
  double* dacc = (double*)(ws + 0);                        // 8 B
  float* gold  = (float*)(ws + 8);                         // 4 B
  float* transT = (float*)(ws + 1024);                     // 4 MB
  size_t off = 1024 + (size_t)LLAB * LLAB * 4;
  u64* pbuf = (u64*)(ws + off);                            // 32*2*8*1024*8 = 4 MB
  const size_t pbytes = (size_t)32 * 2 * NPTY * 1024 * 8;
  off += pbytes;
  float* ybuf = (float*)(ws + off); off += (size_t)NCH * LLAB * 4;   // 1 MB
  float* zbuf = (float*)(ws + off); off += (size_t)NCH * LLAB * 4;   // 1 MB
  double* tlog = (double*)(ws + off);                      // 2 KB

  hipMemsetAsync(ws, 0, 256, stream);            // dacc + gold
  hipMemsetAsync(pbuf, 0, pbytes, stream);       // clear tags (stale-run aliasing)
  transpose_k<<<1024, 256, 0, stream>>>(trans, transT);
  crf_gold<<<64, 256, 0, stream>>>(pred, ref, trans, gold);
  crf_chunks<<<256, 256, 0, stream>>>(pred, trans, transT, pbuf, ybuf, zbuf, tlog);
  crf_stitch<<<NCH, 256, 0, stream>>>(ybuf, zbuf, tlog, dacc);
  crf_final<<<1, 1, 0, stream>>>(dacc, zbuf, gold, out);
}